// Round 11
// baseline (3041.483 us; speedup 1.0000x reference)
//
#include <hip/hip_runtime.h>

#define HDIM 2048
#define TSTEPS 1024
#define NBLK 128
#define NTHR 1024
#define CPB 16
#define TAGM 0x3FFu
#define NREP 8
#define RSTRIDE 2112u   // u32 per replica = 8KB + 256B (channel decorrelation)
#define SPIN_CAP (1 << 21)   // watchdog: ~1s, never reached in normal runs

typedef unsigned long long ull;

__device__ __forceinline__ int snake_src(int t) {
    int y = t >> 5, p = t & 31;
    return (y & 1) ? (y * 32 + 31 - p) : t;
}
__device__ __forceinline__ float sigmoid_f(float v) {
    return __builtin_amdgcn_rcpf(1.f + __expf(-v));
}
__device__ __forceinline__ float tanh_f(float v) {
    return 1.f - 2.f * __builtin_amdgcn_rcpf(__expf(2.f * v) + 1.f);
}
// broadcast from lane ((lane & 0x10) | J) within the 32-lane half: keeps
// bit 4 (16-lane group id within the half); bit 5 implicitly preserved.
// Our 16-lane groups (same r = tid>>4) are bits 4,5 — closed under this.
template<int J>
__device__ __forceinline__ float bcast16(float v) {
    return __uint_as_float((unsigned)__builtin_amdgcn_ds_swizzle(
        (int)__float_as_uint(v), (J << 5) | 0x10));
}

// raw barrier: drain LDS only; vmem (tag prefetch) stays in flight.
#define BAR_RAW() do { asm volatile("s_waitcnt lgkmcnt(0)" ::: "memory"); \
                       __builtin_amdgcn_s_barrier(); } while (0)

// ---------------------------------------------------------------------------
// R10 resubmit (previous run died at container acquisition — no timing block
// in the bench JSON, same infra signature as R5/R6 which passed unmodified
// as R7). Kernel audited: poll closure, bcast16 mapping, selfcol indexing,
// publish coverage, election ordering all verified; no new liveness hazard.
//
// R10 = RESHAPE 256x512 -> 128x1024 (16 cols/block), everything else R9:
//   - detect wait = max over 128 publishers (was 256): tail shrinks.
//   - each thread polls ONE ull (8B, was 16B): chip-wide poll traffic per
//     sample halves -> less L3 queueing (the R3 mechanism, second helping).
//   - poll closure preserved: 16-lane group (same r=tid>>4) polls exactly
//     rows 32r..32r+31; bcast16 ds_swizzle replaces bcast8. 96 FMAs/thread
//     and 96 weight regs unchanged.
//   - publish: 8 replicas, TWO dword stores per finalizer lane (8 reps x
//     16 cols = 128 dwords = 2 wave-stores). Total bytes (64KB/step) and
//     32B-sector count (2048) IDENTICAL to the proven R3 shape. Pollers
//     per replica unchanged (16 blk x 1024 thr). Ledger L1/L4 intact.
//   - election now old==15; reduce loses a shuffle stage (m=16,32 only).
// Carried: self-bypass sNext, tag prefetch + immediate reload, raw barrier
// (publish before next-step spinning, L2), sleep backoff (L3), watchdog.
// VGPR note: 16 waves/CU caps at 128 VGPR; hot loop ~125. launch_bounds
// (1024,1) enforces; init-phase spill (one-time) acceptable.
// ---------------------------------------------------------------------------
__global__ __launch_bounds__(NTHR, 1) void gru_all(
    const float* __restrict__ x,
    const float* __restrict__ We,  const float* __restrict__ be,
    const float* __restrict__ Wir, const float* __restrict__ bir,
    const float* __restrict__ Wiz, const float* __restrict__ biz,
    const float* __restrict__ Win, const float* __restrict__ bin_,
    const float* __restrict__ Whr, const float* __restrict__ Whz,
    const float* __restrict__ Whn, const float* __restrict__ bhn,
    float* __restrict__ out, unsigned* __restrict__ u0, unsigned* __restrict__ u1)
{
    const int tid  = threadIdx.x;
    const int blk  = blockIdx.x;
    const int c    = tid & 15;
    const int r    = tid >> 4;            // 0..63
    const int col  = blk * CPB + c;
    const int row0 = r * 32;
    const int lane = tid & 63, wv = tid >> 6;   // 16 waves

    __shared__ float red[16][6][16];      // init-phase cross-wave reduce
    __shared__ float sX[TSTEPS];          // x in snake order
    __shared__ float sAcc[3][16];         // per-step gate accumulators
    __shared__ float sNext[16];           // own 16 cols of h_t (full precision)
    __shared__ float sAN[16];             // input-path n-term for current t
    __shared__ float sVr[16], sVz[16], sVn[16];   // rank-1 row-sums (const)
    __shared__ float sCr[16], sCz[16], sCn[16];   // bias-path consts
    __shared__ float sBh[16];                     // bhn consts
    __shared__ unsigned sCnt;             // waves-done counter

    // ---- one-time: x (snake order) into LDS ----
    for (int i = tid; i < TSTEPS; i += NTHR) sX[i] = x[snake_src(i)];
    if (tid == 0) sCnt = 0u;

    // ---- recurrent weights into registers (one-time) ----
    float wr[32], wz[32], wn[32];
#pragma unroll
    for (int k = 0; k < 32; ++k) {
        size_t off = (size_t)(row0 + k) * HDIM + col;
        wr[k] = Whr[off];
        wz[k] = Whz[off];
        wn[k] = Whn[off];
    }

    // ---- rank-1 input-path constants (We/be direct from global) ----
    float eR=0,eZ=0,eN=0,bRa=0,bZa=0,bNa=0;
#pragma unroll 8
    for (int k = 0; k < 32; ++k) {
        int row = row0 + k;
        size_t off = (size_t)row * HDIM + col;
        float we = We[row], bb = be[row];
        float w0 = Wir[off], w1 = Wiz[off], w2 = Win[off];
        eR  = fmaf(we, w0, eR);  bRa = fmaf(bb, w0, bRa);
        eZ  = fmaf(we, w1, eZ);  bZa = fmaf(bb, w1, bZa);
        eN  = fmaf(we, w2, eN);  bNa = fmaf(bb, w2, bNa);
    }
#pragma unroll
    for (int m = 16; m < 64; m <<= 1) {
        eR  += __shfl_xor(eR,  m, 64); eZ  += __shfl_xor(eZ,  m, 64);
        eN  += __shfl_xor(eN,  m, 64); bRa += __shfl_xor(bRa, m, 64);
        bZa += __shfl_xor(bZa, m, 64); bNa += __shfl_xor(bNa, m, 64);
    }
    if (lane < 16) {
        red[wv][0][lane]=eR;  red[wv][1][lane]=eZ;  red[wv][2][lane]=eN;
        red[wv][3][lane]=bRa; red[wv][4][lane]=bZa; red[wv][5][lane]=bNa;
    }
    __syncthreads();   // red + sX staged

    unsigned pk1 = 0;
    if (tid < 16) {
        float vrc=0,vzc=0,vnc=0,crc=0,czc=0,cnc=0;
#pragma unroll
        for (int w = 0; w < 16; ++w) {
            vrc += red[w][0][tid]; vzc += red[w][1][tid]; vnc += red[w][2][tid];
            crc += red[w][3][tid]; czc += red[w][4][tid]; cnc += red[w][5][tid];
        }
        crc += bir[col]; czc += biz[col]; cnc += bin_[col];
        float bhc = bhn[col];

        // constants -> LDS so ANY wave can finalize/re-init
        sVr[tid]=vrc; sVz[tid]=vzc; sVn[tid]=vnc;
        sCr[tid]=crc; sCz[tid]=czc; sCn[tid]=cnc; sBh[tid]=bhc;

        // ---- step 0: h_0 == 0, fully local; h_1 with tag 1 ----
        float x0 = sX[0];
        float ar = fmaf(x0, vrc, crc);
        float az = fmaf(x0, vzc, czc);
        float an = fmaf(x0, vnc, cnc);
        float rg = sigmoid_f(ar), zg = sigmoid_f(az);
        float ng = tanh_f(fmaf(rg, bhc, an));
        float h1 = (1.f - zg) * ng;
        pk1 = ((__float_as_uint(h1) + 512u) & ~TAGM) | 1u;
        sNext[tid] = h1;                  // self-bypass seed for t=1

        // seed t=1 accumulators + n-term
        float x1 = sX[1];
        sAcc[0][tid] = fmaf(x1, vrc, crc);
        sAcc[1][tid] = fmaf(x1, vzc, czc);
        sAN[tid]     = fmaf(x1, vnc, cnc);
        sAcc[2][tid] = bhc;
    }
    // step-0 publish: 8 replicas via TWO dword stores (R3-equivalent shape)
    if (wv == 0) {
        unsigned pkb = __shfl(pk1, lane & 15, 64);
        unsigned idx = (unsigned)blk * 16u + (unsigned)(lane & 15);
        __hip_atomic_store(&u1[(unsigned)(lane >> 4) * RSTRIDE + idx],
                           pkb, __ATOMIC_RELAXED, __HIP_MEMORY_SCOPE_AGENT);
        __hip_atomic_store(&u1[((unsigned)(lane >> 4) + 4u) * RSTRIDE + idx],
                           pkb, __ATOMIC_RELAXED, __HIP_MEMORY_SCOPE_AGENT);
    }
    __syncthreads();   // LDS state + publish issued before anyone polls

    const ull  M2     = 0x000003FF000003FFull;
    const ull  repoff = (ull)(blk & 7) * (RSTRIDE / 2);   // ull units
    const bool selfcol = ((tid >> 3) == blk);             // polls own cols
    int alive = 1;     // watchdog flag: once 0, never poll again

    // ---- initial prefetch for t=1: ONE ull per thread ----
    ull v0p;
    {
        const ull* pp1 = (const ull*)u1 + repoff + tid;
        v0p = __hip_atomic_load(pp1, __ATOMIC_RELAXED, __HIP_MEMORY_SCOPE_AGENT);
    }

    for (int t = 1; t < TSTEPS; ++t) {
        const unsigned* pin  = (t & 1) ? u1 : u0;
        unsigned*       pout = (t & 1) ? u0 : u1;
        const unsigned  tg   = (unsigned)t & TAGM;
        const ull       tg2  = ((ull)tg << 32) | (ull)tg;

        float hr0, hr1;
        if (selfcol) {
            // own columns: values live in LDS, skip the L3 round-trip
            const float* sn = &sNext[(tid & 7) * 2];
            hr0 = sn[0]; hr1 = sn[1];
        } else {
            ull v0 = v0p;
            if ((v0 ^ tg2) & M2) {
                const ull* pp = (const ull*)pin + repoff + tid;
                // immediate reload (no sleep): prefetch is usually stale-by-
                // timing; a publish may have landed during our FMA phase.
                v0 = __hip_atomic_load(pp, __ATOMIC_RELAXED, __HIP_MEMORY_SCOPE_AGENT);
                if (((v0 ^ tg2) & M2) && alive) {
                    int guard = 0;
                    do {
                        __builtin_amdgcn_s_sleep(1);
                        v0 = __hip_atomic_load(pp, __ATOMIC_RELAXED, __HIP_MEMORY_SCOPE_AGENT);
                        if (++guard > SPIN_CAP) { alive = 0; break; }
                    } while ((v0 ^ tg2) & M2);
                }
            }
            hr0 = __uint_as_float((unsigned)v0         & ~TAGM);
            hr1 = __uint_as_float((unsigned)(v0 >> 32) & ~TAGM);
        }

        // ---- 32 intra-group swizzle broadcasts + 96 FMAs (no barrier) ----
        float a0 = 0.f, a1 = 0.f, a2 = 0.f;
#define GRP(J) { \
        float h0 = bcast16<J>(hr0), h1 = bcast16<J>(hr1); \
        a0 = fmaf(h0, wr[2*J],   a0); a1 = fmaf(h0, wz[2*J],   a1); a2 = fmaf(h0, wn[2*J],   a2); \
        a0 = fmaf(h1, wr[2*J+1], a0); a1 = fmaf(h1, wz[2*J+1], a1); a2 = fmaf(h1, wn[2*J+1], a2); }
        GRP(0)  GRP(1)  GRP(2)  GRP(3)  GRP(4)  GRP(5)  GRP(6)  GRP(7)
        GRP(8)  GRP(9)  GRP(10) GRP(11) GRP(12) GRP(13) GRP(14) GRP(15)
#undef GRP

        // ---- reduce over the 4 r-groups of this wave (2 stages) ----
#pragma unroll
        for (int m = 16; m < 64; m <<= 1) {
            a0 += __shfl_xor(a0, m, 64);
            a1 += __shfl_xor(a1, m, 64);
            a2 += __shfl_xor(a2, m, 64);
        }
        if (lane < 16) {
            atomicAdd(&sAcc[0][lane], a0);
            atomicAdd(&sAcc[1][lane], a1);
            atomicAdd(&sAcc[2][lane], a2);
        }

        // ---- prefetch t+1 slot; stays in flight across the barrier ----
        {
            const ull* ppn = (const ull*)pout + repoff + tid;
            v0p = __hip_atomic_load(ppn, __ATOMIC_RELAXED, __HIP_MEMORY_SCOPE_AGENT);
        }

        // ---- last-finisher election: wave seeing old==15 finalizes NOW ----
        unsigned oldv = 0;
        if (lane == 0) oldv = atomicAdd(&sCnt, 1u);
        oldv = __builtin_amdgcn_readfirstlane(oldv);
        if (oldv == 15u) {
            float hnew = 0.f; unsigned pk = 0;
            if (lane < 16) {
                float Sr = sAcc[0][lane];         // aR + Whr.h
                float Sz = sAcc[1][lane];         // aZ + Whz.h
                float Sn = sAcc[2][lane];         // bhn + Whn.h
                float hold = sNext[lane];         // own h_t, full precision
                float rg = sigmoid_f(Sr), zg = sigmoid_f(Sz);
                float ng = tanh_f(sAN[lane] + rg * Sn);
                hnew = (1.f - zg) * ng + zg * hold;
                pk = ((__float_as_uint(hnew) + 512u) & ~TAGM)
                   | ((unsigned)(t + 1) & TAGM);
            }
            if (t == TSTEPS - 1) {
                if (lane < 16) out[blk * CPB + lane] = hnew;
            } else {
                unsigned pkb = __shfl(pk, lane & 15, 64);
                unsigned idx = (unsigned)blk * 16u + (unsigned)(lane & 15);
                __hip_atomic_store(&pout[(unsigned)(lane >> 4) * RSTRIDE + idx],
                                   pkb, __ATOMIC_RELAXED, __HIP_MEMORY_SCOPE_AGENT);
                __hip_atomic_store(&pout[((unsigned)(lane >> 4) + 4u) * RSTRIDE + idx],
                                   pkb, __ATOMIC_RELAXED, __HIP_MEMORY_SCOPE_AGENT);
                if (lane < 16) {   // self-bypass + re-init for t+1
                    sNext[lane] = hnew;
                    float xn = sX[t + 1];
                    sAcc[0][lane] = fmaf(xn, sVr[lane], sCr[lane]);
                    sAcc[1][lane] = fmaf(xn, sVz[lane], sCz[lane]);
                    sAN[lane]     = fmaf(xn, sVn[lane], sCn[lane]);
                    sAcc[2][lane] = sBh[lane];
                }
                if (lane == 0) sCnt = 0u;
            }
        }
        // single barrier: publish issued + LDS re-init done before anyone
        // proceeds to t+1 (ledger L2); vmem prefetch stays in flight.
        BAR_RAW();
    }
}

extern "C" void kernel_launch(void* const* d_in, const int* in_sizes, int n_in,
                              void* d_out, int out_size, void* d_ws, size_t ws_size,
                              hipStream_t stream) {
    const float* x    = (const float*)d_in[0];
    const float* We   = (const float*)d_in[1];
    const float* be   = (const float*)d_in[2];
    const float* Wir  = (const float*)d_in[3];
    const float* bir  = (const float*)d_in[4];
    const float* Wiz  = (const float*)d_in[5];
    const float* biz  = (const float*)d_in[6];
    const float* Win  = (const float*)d_in[7];
    const float* bin_ = (const float*)d_in[8];
    const float* Whr  = (const float*)d_in[9];
    const float* Whz  = (const float*)d_in[10];
    const float* Whn  = (const float*)d_in[11];
    const float* bhn  = (const float*)d_in[12];

    unsigned* u0 = (unsigned*)d_ws;             // even parity: 8 replicas
    unsigned* u1 = u0 + NREP * RSTRIDE;         // odd parity:  8 replicas
    // total workspace use: 2 * 8 * 2112 * 4B = 132 KB

    gru_all<<<NBLK, NTHR, 0, stream>>>(x, We, be, Wir, bir, Wiz, biz, Win, bin_,
                                       Whr, Whz, Whn, bhn,
                                       (float*)d_out, u0, u1);
}